// Round 6
// baseline (186.139 us; speedup 1.0000x reference)
//
#include <hip/hip_runtime.h>
#include <hip/hip_bf16.h>
#include <cstdint>
#include <cstddef>

// Problem constants
#define BS_TOT 12288   // 3 * 4096 rows
#define DIM    256     // embedding dim
#define BATCH_ 4096
#define NTILE  96      // BS_TOT / 128
#define NPAIR  4656    // NTILE*(NTILE+1)/2 — triangular tile pairs (incl diag)

typedef float f32x16 __attribute__((ext_vector_type(16)));

// ---------------------------------------------------------------------------
// Kernel 1: row-normalize -> fp8 e4m3 rows SCALED BY sqrt(10) (folds the
// 1/temp=10 into the matmul so the epilogue exp needs no multiply; fp8
// quantization error is relative, so scaling costs no accuracy) + fp32
// inv-norms (exact numerator path) + zero den + zero out.
// ---------------------------------------------------------------------------
__global__ __launch_bounds__(256) void normalize_kernel(const float* __restrict__ x,
                                                        uint8_t* __restrict__ xn,
                                                        float* __restrict__ invn,
                                                        float* __restrict__ den,
                                                        float* __restrict__ out,
                                                        int osz) {
  if (blockIdx.x == 0 && (int)threadIdx.x < osz) out[threadIdx.x] = 0.0f;
  const int wave = threadIdx.x >> 6;
  const int lane = threadIdx.x & 63;
  const int row  = blockIdx.x * 4 + wave;
  const float4 v = ((const float4*)(x + (size_t)row * DIM))[lane];
  float ss = v.x*v.x + v.y*v.y + v.z*v.z + v.w*v.w;
  #pragma unroll
  for (int off = 1; off < 64; off <<= 1) ss += __shfl_xor(ss, off, 64);
  const float s = 1.0f / fmaxf(sqrtf(ss), 1e-6f);
  if (lane == 0) { invn[row] = s; den[row] = 0.0f; }
  const float sc = s * 3.16227766016838f;   // sqrt(10): so acc = 10*cos
  unsigned int w = __builtin_amdgcn_cvt_pk_fp8_f32(v.x * sc, v.y * sc, 0u, false);
  w = __builtin_amdgcn_cvt_pk_fp8_f32(v.z * sc, v.w * sc, w, true);
  ((unsigned int*)(xn + (size_t)row * DIM))[lane] = w;
}

// ---------------------------------------------------------------------------
// Kernel 2: SYMMETRIC triangular tile grid (tI <= tJ) of A@A^T (fp8 e4m3,
// 32x32x16 MFMA), exp-fused, masked row AND column sums into den.
//
// R5 structure (proven: MfmaUtil 41%): both operands staged once in LDS via
// coalesced dwordx4 + XOR-swizzled ds_write_b64
//   slot8(row,k8) = row*32 + (k8 ^ (row&31))   -> <=2-way bank alias (free),
// one barrier, 4 waves in 2x2 (each 64x64 via 2x2 of 32x32x16).
//
// Symmetry: E and the mod-4 mask are symmetric. For tI<tJ the tile's masked
// COLUMN sums (in-register over rows: free) go to den[cols in tJ] and its
// masked ROW sums (5 shfl over the 32 col-lanes per (mi,r)) go to
// den[rows in tI] — the transpose tile's contribution. Diagonal tiles:
// column sums only (counted once). MFMA floor halves vs the R5 full grid.
//
// C/D layout (HW-verified, dtype-independent): col = lane&31,
// row = (reg&3) + 8*(reg>>2) + 4*(lane>>5).
// Mask: exclude iff col%4 == row%4  ->  ((l31 ^ r) & 3) == 0.
// ---------------------------------------------------------------------------
__global__ __launch_bounds__(256, 2) void gemm_den_kernel(const uint8_t* __restrict__ xn,
                                                          float* __restrict__ den) {
  __shared__ unsigned long long As[128 * 32];   // 32 KB, swizzled 8-B slots
  __shared__ unsigned long long Bs[128 * 32];   // 32 KB

  const int tid = threadIdx.x;

  // triangular decode: blockIdx.x -> (tI <= tJ)
  const int t = blockIdx.x;
  int j = (int)((sqrtf(8.0f * (float)t + 1.0f) - 1.0f) * 0.5f);
  while ((j + 1) * (j + 2) / 2 <= t) j++;
  while (j * (j + 1) / 2 > t) j--;
  const int tI = t - j * (j + 1) / 2;   // 0..j
  const int tJ = j;

  const int wave = tid >> 6, lane = tid & 63;
  const int wr   = wave >> 1, wc = wave & 1;
  const int l31  = lane & 31, half = lane >> 5;

  const uint8_t* Ab = xn + (size_t)tI * 128 * DIM;
  const uint8_t* Bb = xn + (size_t)tJ * 128 * DIM;

  // ---- Stage A and B: per thread 8 chunks of 16 B (coalesced), then two
  // swizzled 8-B LDS writes per chunk.
  ulonglong2 chA[8], chB[8];
  #pragma unroll
  for (int c = 0; c < 8; c++) {
    const int q = c * 256 + tid;
    const size_t off = (size_t)(q >> 4) * DIM + (size_t)(q & 15) * 16;
    chA[c] = *(const ulonglong2*)(Ab + off);
    chB[c] = *(const ulonglong2*)(Bb + off);
  }
  #pragma unroll
  for (int c = 0; c < 8; c++) {
    const int q = c * 256 + tid;
    const int row = q >> 4, k16 = q & 15;
    const int s0 = row * 32 + ((2 * k16)     ^ (row & 31));
    const int s1 = row * 32 + ((2 * k16 + 1) ^ (row & 31));
    As[s0] = chA[c].x; As[s1] = chA[c].y;
    Bs[s0] = chB[c].x; Bs[s1] = chB[c].y;
  }
  __syncthreads();   // the ONLY barrier

  // ---- K-loop: 16 steps of K=16; per step 2 A-frag + 2 B-frag swizzled
  // ds_read_b64 + 4 MFMA. Frag: lane holds 8 bytes of row (l31),
  // k = ks*16 + half*8  ->  k8 index = 2*ks + half.
  f32x16 acc[2][2] = {};
  #pragma unroll
  for (int ks = 0; ks < 16; ks++) {
    long af[2], bf[2];
    #pragma unroll
    for (int mi = 0; mi < 2; mi++) {
      const int row = wr * 64 + mi * 32 + l31;
      af[mi] = (long)As[row * 32 + ((2 * ks + half) ^ (row & 31))];
    }
    #pragma unroll
    for (int ni = 0; ni < 2; ni++) {
      const int row = wc * 64 + ni * 32 + l31;
      bf[ni] = (long)Bs[row * 32 + ((2 * ks + half) ^ (row & 31))];
    }
    #pragma unroll
    for (int mi = 0; mi < 2; mi++)
      #pragma unroll
      for (int ni = 0; ni < 2; ni++)
        acc[mi][ni] = __builtin_amdgcn_mfma_f32_32x32x16_fp8_fp8(af[mi], bf[ni], acc[mi][ni], 0, 0, 0);
  }

  // ---- Epilogue: E = exp(acc) (temp pre-folded). Column sums in-register;
  // row sums (off-diagonal only) via 5 shfl over the 32 col-lanes.
  const int rowBase = tI * 128 + wr * 64;
  const int colBase = tJ * 128 + wc * 64;
  const bool offd = (tI != tJ);
  float colsum[2] = {0.f, 0.f};

  #pragma unroll
  for (int mi = 0; mi < 2; mi++) {
    #pragma unroll
    for (int r = 0; r < 16; r++) {
      const bool inc = ((l31 ^ r) & 3) != 0;   // col%4 != row%4
      const float e0 = inc ? __expf(acc[mi][0][r]) : 0.0f;
      const float e1 = inc ? __expf(acc[mi][1][r]) : 0.0f;
      colsum[0] += e0;
      colsum[1] += e1;
      if (offd) {
        float rv = e0 + e1;                    // this lane's row contribution
        rv += __shfl_xor(rv, 1, 64);
        rv += __shfl_xor(rv, 2, 64);
        rv += __shfl_xor(rv, 4, 64);
        rv += __shfl_xor(rv, 8, 64);
        rv += __shfl_xor(rv, 16, 64);
        if (l31 == 0)                          // lanes 0 and 32 (both halves)
          atomicAdd(&den[rowBase + mi*32 + (r & 3) + 8*(r >> 2) + 4*half], rv);
      }
    }
  }
  #pragma unroll
  for (int ni = 0; ni < 2; ni++) {
    float cs = colsum[ni] + __shfl_xor(colsum[ni], 32, 64);
    if (half == 0) atomicAdd(&den[colBase + ni * 32 + l31], cs);
  }
}

// ---------------------------------------------------------------------------
// Kernel 3: numerators (fp32, exact path) + final loss.
// ---------------------------------------------------------------------------
__global__ __launch_bounds__(256) void loss_kernel(const float* __restrict__ x,
                                                   const float* __restrict__ invn,
                                                   const float* __restrict__ den,
                                                   float* __restrict__ out) {
  __shared__ float part[4];
  const int wave = threadIdx.x >> 6, lane = threadIdx.x & 63;
  const int p = blockIdx.x * 4 + wave;
  const float4 a = ((const float4*)(x + (size_t)p * DIM))[lane];
  const float4 b = ((const float4*)(x + (size_t)(BATCH_ + p) * DIM))[lane];
  const float4 c = ((const float4*)(x + (size_t)(2*BATCH_ + p) * DIM))[lane];
  float d12 = a.x*b.x + a.y*b.y + a.z*b.z + a.w*b.w;
  float d13 = a.x*c.x + a.y*c.y + a.z*c.z + a.w*c.w;
  float d23 = b.x*c.x + b.y*c.y + b.z*c.z + b.w*c.w;
  #pragma unroll
  for (int off = 1; off < 64; off <<= 1) {
    d12 += __shfl_xor(d12, off, 64);
    d13 += __shfl_xor(d13, off, 64);
    d23 += __shfl_xor(d23, off, 64);
  }
  if (lane == 0) {
    const float s1 = invn[p], s2 = invn[BATCH_ + p], s3 = invn[2*BATCH_ + p];
    const float z12 = d12 * s1 * s2 * 10.0f;
    const float z13 = d13 * s1 * s3 * 10.0f;
    const float z23 = d23 * s2 * s3 * 10.0f;
    const float n12 = __expf(z12), n13 = __expf(z13), n23 = __expf(z23);
    const float e1 = den[p], e2 = den[BATCH_ + p], e3 = den[2*BATCH_ + p];
    part[wave] = __logf(n12 + e1) + __logf(n12 + e2) - 2.0f * z12
               + __logf(n13 + e1) + __logf(n13 + e3) - 2.0f * z13
               + __logf(n23 + e2) + __logf(n23 + e3) - 2.0f * z23;
  }
  __syncthreads();
  if (threadIdx.x == 0) {
    atomicAdd(out, (part[0] + part[1] + part[2] + part[3]) * (1.0f / (2.0f * BATCH_)));
  }
}

// ---------------------------------------------------------------------------
extern "C" void kernel_launch(void* const* d_in, const int* in_sizes, int n_in,
                              void* d_out, int out_size, void* d_ws, size_t ws_size,
                              hipStream_t stream) {
  const float* x = (const float*)d_in[0];
  float* out = (float*)d_out;

  char* ws = (char*)d_ws;
  uint8_t* xn   = (uint8_t*)ws;                                      // 3 MB fp8
  float*   invn = (float*)(ws + (size_t)BS_TOT * DIM);               // 48 KB
  float*   den  = (float*)(ws + (size_t)BS_TOT * DIM + BS_TOT * 4);  // 48 KB

  normalize_kernel<<<BS_TOT / 4, 256, 0, stream>>>(x, xn, invn, den, out, out_size);
  gemm_den_kernel<<<NPAIR, 256, 0, stream>>>(xn, den);
  loss_kernel<<<BATCH_ / 4, 256, 0, stream>>>(x, invn, den, out);
}

// Round 7
// 131.482 us; speedup vs baseline: 1.4157x; 1.4157x over previous
//
#include <hip/hip_runtime.h>
#include <hip/hip_bf16.h>
#include <cstdint>
#include <cstddef>

// Problem constants
#define BS_TOT 12288   // 3 * 4096 rows
#define DIM    256     // embedding dim
#define BATCH_ 4096
#define NTILE  96      // BS_TOT / 128

typedef float f32x16 __attribute__((ext_vector_type(16)));
typedef int   i32x8  __attribute__((ext_vector_type(8)));

// ---------------------------------------------------------------------------
// Kernel 1: row-normalize -> fp8 e4m3 rows scaled by sqrt(10) (temp folded
// into the matmul: acc = 10*cos, epilogue exp needs no multiply) + fp32
// inv-norms (exact numerator path) + zero den + zero out.
// ---------------------------------------------------------------------------
__global__ __launch_bounds__(256) void normalize_kernel(const float* __restrict__ x,
                                                        uint8_t* __restrict__ xn,
                                                        float* __restrict__ invn,
                                                        float* __restrict__ den,
                                                        float* __restrict__ out,
                                                        int osz) {
  if (blockIdx.x == 0 && (int)threadIdx.x < osz) out[threadIdx.x] = 0.0f;
  const int wave = threadIdx.x >> 6;
  const int lane = threadIdx.x & 63;
  const int row  = blockIdx.x * 4 + wave;
  const float4 v = ((const float4*)(x + (size_t)row * DIM))[lane];
  float ss = v.x*v.x + v.y*v.y + v.z*v.z + v.w*v.w;
  #pragma unroll
  for (int off = 1; off < 64; off <<= 1) ss += __shfl_xor(ss, off, 64);
  const float s = 1.0f / fmaxf(sqrtf(ss), 1e-6f);
  if (lane == 0) { invn[row] = s; den[row] = 0.0f; }
  const float sc = s * 3.16227766016838f;   // sqrt(10)
  unsigned int w = __builtin_amdgcn_cvt_pk_fp8_f32(v.x * sc, v.y * sc, 0u, false);
  w = __builtin_amdgcn_cvt_pk_fp8_f32(v.z * sc, v.w * sc, w, true);
  ((unsigned int*)(xn + (size_t)row * DIM))[lane] = w;
}

// ---------------------------------------------------------------------------
// Build a v8i32 MFMA operand from 32 contiguous LDS bytes (2 x b128).
// ---------------------------------------------------------------------------
__device__ __forceinline__ i32x8 ld_frag32(const uint8_t* p) {
  const int4 lo = *(const int4*)p;
  const int4 hi = *(const int4*)(p + 16);
  i32x8 r;
  r[0] = lo.x; r[1] = lo.y; r[2] = lo.z; r[3] = lo.w;
  r[4] = hi.x; r[5] = hi.y; r[6] = hi.z; r[7] = hi.w;
  return r;
}

// ---------------------------------------------------------------------------
// Kernel 2: full ordered tile grid (96x96, R5-proven structure) of A@A^T,
// now with MX-scaled fp8 MFMA 32x32x64 (scale = 1.0): 2x MFMA rate, 16
// MFMA/wave instead of 64, 32 ds_read_b128 instead of 64 ds_read_b64.
//
// LDS layout: 32-byte-unit XOR swizzle, unit(row,k32) = k32 ^ (row&7):
//   byte addr = row*256 + (k32 ^ (row&7))*32 + (k16&1)*16
// Fragment for K-step ks (K=64): lane (l31=row%32, half) needs bytes
// k = ks*64 + half*32 + [0..31]  ->  unit (2*ks+half) ^ (l31&7), one
// contiguous 32-B run = 2 x ds_read_b128 (+16 imm).
// Operand layout (m148-family, ref-checked at 16x16x128): k contiguous
// per lane, k = half*32 + j. C/D layout: shape-determined (HW-verified):
// col = lane&31, row = (reg&3) + 8*(reg>>2) + 4*(lane>>5).
//
// Epilogue: masked COLUMN sums only (in-register over rows = free; E and
// the mod-4 mask are symmetric so column sums over the full grid = den).
// Mask: exclude iff col%4 == row%4  ->  ((l31 ^ r) & 3) == 0.
// ---------------------------------------------------------------------------
__global__ __launch_bounds__(256, 2) void gemm_den_kernel(const uint8_t* __restrict__ xn,
                                                          float* __restrict__ den) {
  __shared__ __align__(16) uint8_t As[128 * 256];   // 32 KB
  __shared__ __align__(16) uint8_t Bs[128 * 256];   // 32 KB

  const int tid = threadIdx.x;
  const int tJ  = blockIdx.x;    // column tile
  const int tI  = blockIdx.y;    // row tile

  const int wave = tid >> 6, lane = tid & 63;
  const int wr   = wave >> 1, wc = wave & 1;
  const int l31  = lane & 31, half = lane >> 5;

  const uint8_t* Ab = xn + (size_t)tI * 128 * DIM;
  const uint8_t* Bb = xn + (size_t)tJ * 128 * DIM;

  // ---- Stage A and B: per thread 8 chunks of 16 B (coalesced reads), one
  // swizzled b128 LDS write each.
  int4 chA[8], chB[8];
  #pragma unroll
  for (int c = 0; c < 8; c++) {
    const int q = c * 256 + tid;
    const size_t off = (size_t)(q >> 4) * DIM + (size_t)(q & 15) * 16;
    chA[c] = *(const int4*)(Ab + off);
    chB[c] = *(const int4*)(Bb + off);
  }
  #pragma unroll
  for (int c = 0; c < 8; c++) {
    const int q   = c * 256 + tid;
    const int row = q >> 4, k16 = q & 15;
    const int wa  = row * 256 + (((k16 >> 1) ^ (row & 7)) * 32) + (k16 & 1) * 16;
    *(int4*)(As + wa) = chA[c];
    *(int4*)(Bs + wa) = chB[c];
  }
  __syncthreads();   // the ONLY barrier

  // ---- K-loop: 4 steps of K=64; per step 2 A-frags + 2 B-frags
  // (2 x b128 each) + 4 scaled MFMA.
  const int e7 = l31 & 7;
  const int rowA0 = (wr * 64 + l31) * 256;
  const int rowB0 = (wc * 64 + l31) * 256;

  f32x16 acc[2][2] = {};
  #pragma unroll
  for (int ks = 0; ks < 4; ks++) {
    const int u = ((2 * ks + half) ^ e7) * 32;
    i32x8 af[2], bf[2];
    af[0] = ld_frag32(As + rowA0 + u);
    af[1] = ld_frag32(As + rowA0 + 32 * 256 + u);
    bf[0] = ld_frag32(Bs + rowB0 + u);
    bf[1] = ld_frag32(Bs + rowB0 + 32 * 256 + u);
    #pragma unroll
    for (int mi = 0; mi < 2; mi++)
      #pragma unroll
      for (int ni = 0; ni < 2; ni++)
        acc[mi][ni] = __builtin_amdgcn_mfma_scale_f32_32x32x64_f8f6f4(
            af[mi], bf[ni], acc[mi][ni],
            0, 0,                       // cbsz=fp8(e4m3), blgp=fp8(e4m3)
            0, 0x7F7F7F7F,              // scale A: opsel 0, E8M0 127 = 1.0
            0, 0x7F7F7F7F);             // scale B: opsel 0, 1.0
  }

  // ---- Epilogue: E = exp(acc) (temp pre-folded); masked column sums.
  const int colBase = tJ * 128 + wc * 64;
  #pragma unroll
  for (int ni = 0; ni < 2; ni++) {
    float cs = 0.0f;
    #pragma unroll
    for (int mi = 0; mi < 2; mi++)
      #pragma unroll
      for (int r = 0; r < 16; r++)
        if (((l31 ^ r) & 3) != 0)        // include iff col%4 != row%4
          cs += __expf(acc[mi][ni][r]);
    cs += __shfl_xor(cs, 32, 64);
    if (half == 0) atomicAdd(&den[colBase + ni * 32 + l31], cs);
  }
}

// ---------------------------------------------------------------------------
// Kernel 3: numerators (fp32, exact path) + final loss.
// ---------------------------------------------------------------------------
__global__ __launch_bounds__(256) void loss_kernel(const float* __restrict__ x,
                                                   const float* __restrict__ invn,
                                                   const float* __restrict__ den,
                                                   float* __restrict__ out) {
  __shared__ float part[4];
  const int wave = threadIdx.x >> 6, lane = threadIdx.x & 63;
  const int p = blockIdx.x * 4 + wave;
  const float4 a = ((const float4*)(x + (size_t)p * DIM))[lane];
  const float4 b = ((const float4*)(x + (size_t)(BATCH_ + p) * DIM))[lane];
  const float4 c = ((const float4*)(x + (size_t)(2*BATCH_ + p) * DIM))[lane];
  float d12 = a.x*b.x + a.y*b.y + a.z*b.z + a.w*b.w;
  float d13 = a.x*c.x + a.y*c.y + a.z*c.z + a.w*c.w;
  float d23 = b.x*c.x + b.y*c.y + b.z*c.z + b.w*c.w;
  #pragma unroll
  for (int off = 1; off < 64; off <<= 1) {
    d12 += __shfl_xor(d12, off, 64);
    d13 += __shfl_xor(d13, off, 64);
    d23 += __shfl_xor(d23, off, 64);
  }
  if (lane == 0) {
    const float s1 = invn[p], s2 = invn[BATCH_ + p], s3 = invn[2*BATCH_ + p];
    const float z12 = d12 * s1 * s2 * 10.0f;
    const float z13 = d13 * s1 * s3 * 10.0f;
    const float z23 = d23 * s2 * s3 * 10.0f;
    const float n12 = __expf(z12), n13 = __expf(z13), n23 = __expf(z23);
    const float e1 = den[p], e2 = den[BATCH_ + p], e3 = den[2*BATCH_ + p];
    part[wave] = __logf(n12 + e1) + __logf(n12 + e2) - 2.0f * z12
               + __logf(n13 + e1) + __logf(n13 + e3) - 2.0f * z13
               + __logf(n23 + e2) + __logf(n23 + e3) - 2.0f * z23;
  }
  __syncthreads();
  if (threadIdx.x == 0) {
    atomicAdd(out, (part[0] + part[1] + part[2] + part[3]) * (1.0f / (2.0f * BATCH_)));
  }
}

// ---------------------------------------------------------------------------
extern "C" void kernel_launch(void* const* d_in, const int* in_sizes, int n_in,
                              void* d_out, int out_size, void* d_ws, size_t ws_size,
                              hipStream_t stream) {
  const float* x = (const float*)d_in[0];
  float* out = (float*)d_out;

  char* ws = (char*)d_ws;
  uint8_t* xn   = (uint8_t*)ws;                                      // 3 MB fp8
  float*   invn = (float*)(ws + (size_t)BS_TOT * DIM);               // 48 KB
  float*   den  = (float*)(ws + (size_t)BS_TOT * DIM + BS_TOT * 4);  // 48 KB

  normalize_kernel<<<BS_TOT / 4, 256, 0, stream>>>(x, xn, invn, den, out, out_size);
  gemm_den_kernel<<<dim3(NTILE, NTILE), 256, 0, stream>>>(xn, den);
  loss_kernel<<<BATCH_ / 4, 256, 0, stream>>>(x, invn, den, out);
}

// Round 8
// 125.967 us; speedup vs baseline: 1.4777x; 1.0438x over previous
//
#include <hip/hip_runtime.h>
#include <hip/hip_bf16.h>
#include <cstdint>
#include <cstddef>

// Problem constants
#define BS_TOT 12288   // 3 * 4096 rows
#define DIM    256     // embedding dim
#define BATCH_ 4096
#define NTILE  96      // BS_TOT / 128
#define NPAIR  4656    // NTILE*(NTILE+1)/2 — triangular tile pairs (incl diag)

typedef float f32x16 __attribute__((ext_vector_type(16)));
typedef int   i32x8  __attribute__((ext_vector_type(8)));

// ---------------------------------------------------------------------------
// Kernel 1: row-normalize -> fp8 e4m3 rows scaled by sqrt(10) (temp folded
// into the matmul: acc = 10*cos) + fp32 inv-norms (exact numerator path) +
// zero den + zero out.
// ---------------------------------------------------------------------------
__global__ __launch_bounds__(256) void normalize_kernel(const float* __restrict__ x,
                                                        uint8_t* __restrict__ xn,
                                                        float* __restrict__ invn,
                                                        float* __restrict__ den,
                                                        float* __restrict__ out,
                                                        int osz) {
  if (blockIdx.x == 0 && (int)threadIdx.x < osz) out[threadIdx.x] = 0.0f;
  const int wave = threadIdx.x >> 6;
  const int lane = threadIdx.x & 63;
  const int row  = blockIdx.x * 4 + wave;
  const float4 v = ((const float4*)(x + (size_t)row * DIM))[lane];
  float ss = v.x*v.x + v.y*v.y + v.z*v.z + v.w*v.w;
  #pragma unroll
  for (int off = 1; off < 64; off <<= 1) ss += __shfl_xor(ss, off, 64);
  const float s = 1.0f / fmaxf(sqrtf(ss), 1e-6f);
  if (lane == 0) { invn[row] = s; den[row] = 0.0f; }
  const float sc = s * 3.16227766016838f;   // sqrt(10)
  unsigned int w = __builtin_amdgcn_cvt_pk_fp8_f32(v.x * sc, v.y * sc, 0u, false);
  w = __builtin_amdgcn_cvt_pk_fp8_f32(v.z * sc, v.w * sc, w, true);
  ((unsigned int*)(xn + (size_t)row * DIM))[lane] = w;
}

// ---------------------------------------------------------------------------
// Build a v8i32 MFMA operand from 32 contiguous LDS bytes (2 x b128).
// ---------------------------------------------------------------------------
__device__ __forceinline__ i32x8 ld_frag32(const uint8_t* p) {
  const int4 lo = *(const int4*)p;
  const int4 hi = *(const int4*)(p + 16);
  i32x8 r;
  r[0] = lo.x; r[1] = lo.y; r[2] = lo.z; r[3] = lo.w;
  r[4] = hi.x; r[5] = hi.y; r[6] = hi.z; r[7] = hi.w;
  return r;
}

// ---------------------------------------------------------------------------
// Kernel 2: SYMMETRIC triangular tile grid (tI <= tJ), MX-scaled fp8 MFMA
// 32x32x64. Each block stages panel A (tile tI) and panel B (tile tJ) once
// (R7-proven layout), then computes BOTH tiles of the symmetric pair in one
// K-loop, reusing the same LDS fragments:
//   acc [mi][ni] = A·B^T  -> masked col sums (in-register) -> den[tJ cols]
//   accT[ni][mi] = B·A^T  -> masked col sums (in-register) -> den[tI cols]
// (E and the mod-4 mask are symmetric, so column sums over all ordered
// tiles = den; the pair (I,J)+(J,I) is produced here with zero extra LDS
// traffic and zero cross-lane shuffles — the fix for R6's regression.)
// Diagonal blocks (tI==tJ) compute acc only.
//
// LDS: 32-B-unit XOR swizzle  addr = row*256 + ((k32 ^ (row&7))*32) + sub16
// Fragment ks: lane (l31,half) reads 32 B at unit (2ks+half)^(l31&7).
// Operand layout (m148-family): k contiguous per lane, k = half*32+[0..31].
// C/D (HW-verified, shape-determined): col = lane&31,
// row = (reg&3) + 8*(reg>>2) + 4*(lane>>5).
// Mask: exclude iff col%4 == row%4  ->  ((l31 ^ r) & 3) == 0.
// ---------------------------------------------------------------------------
__global__ __launch_bounds__(256, 2) void gemm_den_kernel(const uint8_t* __restrict__ xn,
                                                          float* __restrict__ den) {
  __shared__ __align__(16) uint8_t As[128 * 256];   // 32 KB
  __shared__ __align__(16) uint8_t Bs[128 * 256];   // 32 KB

  const int tid = threadIdx.x;

  // triangular decode: blockIdx.x -> (tI <= tJ)
  const int t = blockIdx.x;
  int j = (int)((sqrtf(8.0f * (float)t + 1.0f) - 1.0f) * 0.5f);
  while ((j + 1) * (j + 2) / 2 <= t) j++;
  while (j * (j + 1) / 2 > t) j--;
  const int tI = t - j * (j + 1) / 2;   // 0..j
  const int tJ = j;
  const bool offd = (tI != tJ);

  const int wave = tid >> 6, lane = tid & 63;
  const int wr   = wave >> 1, wc = wave & 1;
  const int l31  = lane & 31, half = lane >> 5;

  const uint8_t* Ab = xn + (size_t)tI * 128 * DIM;
  const uint8_t* Bb = xn + (size_t)tJ * 128 * DIM;

  // ---- Stage A and B: 8 coalesced 16-B chunks each, swizzled b128 writes.
  int4 chA[8], chB[8];
  #pragma unroll
  for (int c = 0; c < 8; c++) {
    const int q = c * 256 + tid;
    const size_t off = (size_t)(q >> 4) * DIM + (size_t)(q & 15) * 16;
    chA[c] = *(const int4*)(Ab + off);
    chB[c] = *(const int4*)(Bb + off);
  }
  #pragma unroll
  for (int c = 0; c < 8; c++) {
    const int q   = c * 256 + tid;
    const int row = q >> 4, k16 = q & 15;
    const int wa  = row * 256 + (((k16 >> 1) ^ (row & 7)) * 32) + (k16 & 1) * 16;
    *(int4*)(As + wa) = chA[c];
    *(int4*)(Bs + wa) = chB[c];
  }
  __syncthreads();   // the ONLY barrier

  // ---- K-loop: 4 steps of K=64; 4 frag loads + 8 MFMA (4 fwd + 4 mirror).
  const int e7 = l31 & 7;
  const int rowA0 = (wr * 64 + l31) * 256;
  const int rowB0 = (wc * 64 + l31) * 256;

  f32x16 acc[2][2]  = {};
  f32x16 accT[2][2] = {};
  #pragma unroll
  for (int ks = 0; ks < 4; ks++) {
    const int u = ((2 * ks + half) ^ e7) * 32;
    i32x8 af[2], bf[2];
    af[0] = ld_frag32(As + rowA0 + u);
    af[1] = ld_frag32(As + rowA0 + 32 * 256 + u);
    bf[0] = ld_frag32(Bs + rowB0 + u);
    bf[1] = ld_frag32(Bs + rowB0 + 32 * 256 + u);
    #pragma unroll
    for (int mi = 0; mi < 2; mi++)
      #pragma unroll
      for (int ni = 0; ni < 2; ni++)
        acc[mi][ni] = __builtin_amdgcn_mfma_scale_f32_32x32x64_f8f6f4(
            af[mi], bf[ni], acc[mi][ni], 0, 0, 0, 0x7F7F7F7F, 0, 0x7F7F7F7F);
    if (offd) {
      #pragma unroll
      for (int ni = 0; ni < 2; ni++)
        #pragma unroll
        for (int mi = 0; mi < 2; mi++)
          accT[ni][mi] = __builtin_amdgcn_mfma_scale_f32_32x32x64_f8f6f4(
              bf[ni], af[mi], accT[ni][mi], 0, 0, 0, 0x7F7F7F7F, 0, 0x7F7F7F7F);
    }
  }

  // ---- Epilogue: E = exp(acc) (temp pre-folded); masked column sums.
  // Forward tile: cols belong to tJ (wc strip, index l31 within mi... ni strip).
  const int colBaseF = tJ * 128 + wc * 64;
  #pragma unroll
  for (int ni = 0; ni < 2; ni++) {
    float cs = 0.0f;
    #pragma unroll
    for (int mi = 0; mi < 2; mi++)
      #pragma unroll
      for (int r = 0; r < 16; r++)
        if (((l31 ^ r) & 3) != 0)
          cs += __expf(acc[mi][ni][r]);
    cs += __shfl_xor(cs, 32, 64);
    if (half == 0) atomicAdd(&den[colBaseF + ni * 32 + l31], cs);
  }
  // Mirror tile: cols belong to tI (wr strip).
  if (offd) {
    const int colBaseT = tI * 128 + wr * 64;
    #pragma unroll
    for (int mi = 0; mi < 2; mi++) {
      float cs = 0.0f;
      #pragma unroll
      for (int ni = 0; ni < 2; ni++)
        #pragma unroll
        for (int r = 0; r < 16; r++)
          if (((l31 ^ r) & 3) != 0)
            cs += __expf(accT[ni][mi][r]);
      cs += __shfl_xor(cs, 32, 64);
      if (half == 0) atomicAdd(&den[colBaseT + mi * 32 + l31], cs);
    }
  }
}

// ---------------------------------------------------------------------------
// Kernel 3: numerators (fp32, exact path) + final loss.
// ---------------------------------------------------------------------------
__global__ __launch_bounds__(256) void loss_kernel(const float* __restrict__ x,
                                                   const float* __restrict__ invn,
                                                   const float* __restrict__ den,
                                                   float* __restrict__ out) {
  __shared__ float part[4];
  const int wave = threadIdx.x >> 6, lane = threadIdx.x & 63;
  const int p = blockIdx.x * 4 + wave;
  const float4 a = ((const float4*)(x + (size_t)p * DIM))[lane];
  const float4 b = ((const float4*)(x + (size_t)(BATCH_ + p) * DIM))[lane];
  const float4 c = ((const float4*)(x + (size_t)(2*BATCH_ + p) * DIM))[lane];
  float d12 = a.x*b.x + a.y*b.y + a.z*b.z + a.w*b.w;
  float d13 = a.x*c.x + a.y*c.y + a.z*c.z + a.w*c.w;
  float d23 = b.x*c.x + b.y*c.y + b.z*c.z + b.w*c.w;
  #pragma unroll
  for (int off = 1; off < 64; off <<= 1) {
    d12 += __shfl_xor(d12, off, 64);
    d13 += __shfl_xor(d13, off, 64);
    d23 += __shfl_xor(d23, off, 64);
  }
  if (lane == 0) {
    const float s1 = invn[p], s2 = invn[BATCH_ + p], s3 = invn[2*BATCH_ + p];
    const float z12 = d12 * s1 * s2 * 10.0f;
    const float z13 = d13 * s1 * s3 * 10.0f;
    const float z23 = d23 * s2 * s3 * 10.0f;
    const float n12 = __expf(z12), n13 = __expf(z13), n23 = __expf(z23);
    const float e1 = den[p], e2 = den[BATCH_ + p], e3 = den[2*BATCH_ + p];
    part[wave] = __logf(n12 + e1) + __logf(n12 + e2) - 2.0f * z12
               + __logf(n13 + e1) + __logf(n13 + e3) - 2.0f * z13
               + __logf(n23 + e2) + __logf(n23 + e3) - 2.0f * z23;
  }
  __syncthreads();
  if (threadIdx.x == 0) {
    atomicAdd(out, (part[0] + part[1] + part[2] + part[3]) * (1.0f / (2.0f * BATCH_)));
  }
}

// ---------------------------------------------------------------------------
extern "C" void kernel_launch(void* const* d_in, const int* in_sizes, int n_in,
                              void* d_out, int out_size, void* d_ws, size_t ws_size,
                              hipStream_t stream) {
  const float* x = (const float*)d_in[0];
  float* out = (float*)d_out;

  char* ws = (char*)d_ws;
  uint8_t* xn   = (uint8_t*)ws;                                      // 3 MB fp8
  float*   invn = (float*)(ws + (size_t)BS_TOT * DIM);               // 48 KB
  float*   den  = (float*)(ws + (size_t)BS_TOT * DIM + BS_TOT * 4);  // 48 KB

  normalize_kernel<<<BS_TOT / 4, 256, 0, stream>>>(x, xn, invn, den, out, out_size);
  gemm_den_kernel<<<NPAIR, 256, 0, stream>>>(xn, den);
  loss_kernel<<<BATCH_ / 4, 256, 0, stream>>>(x, invn, den, out);
}